// Round 5
// baseline (3385.510 us; speedup 1.0000x reference)
//
#include <hip/hip_runtime.h>
#include <cstdint>
#include <cstddef>

#define B_ 512
#define S_ 336
#define F_ 16
#define H_ 256
#define P_ 48

typedef __bf16 bhalf;
typedef __attribute__((ext_vector_type(8))) __bf16 bhalf8;
typedef __attribute__((ext_vector_type(4))) float f32x4;

#define MFMA16(A, Bv, C) __builtin_amdgcn_mfma_f32_16x16x32_bf16((A), (Bv), (C), 0, 0, 0)

__device__ __forceinline__ float fastrcp(float x) { return __builtin_amdgcn_rcpf(x); }
__device__ __forceinline__ float sigm(float x) { return fastrcp(1.0f + __expf(-x)); }
__device__ __forceinline__ float tanh_f(float x) { return 2.0f * fastrcp(1.0f + __expf(-2.0f * x)) - 1.0f; }

__device__ __forceinline__ bhalf u16_to_bf(unsigned int u) {
  return __builtin_bit_cast(__bf16, (unsigned short)u);
}
__device__ __forceinline__ unsigned short bf_to_u16(bhalf b) {
  return __builtin_bit_cast(unsigned short, b);
}

__device__ __forceinline__ bhalf8 bzero8() {
  bhalf8 v;
#pragma unroll
  for (int j = 0; j < 8; ++j) v[j] = (bhalf)0.0f;
  return v;
}

// ---------------------------------------------------------------------------
// Encoder: weight-stationary MFMA flag pipeline.
// CHANGE vs r4 (geometry only, protocol identical): 512 blocks = 2 blocks/CU.
// r4 counters: ~85% of each 11.7Kcy step is stall (MFMA 660cy + VALU 900cy
// busy) — agent-scope hpack exchange is structurally L3-latency-bound (sc1
// bypasses per-XCD L2; nt hints were a no-op). Fix: co-resident second block
// from an INDEPENDENT group overlaps one group's spin with the other's
// compute. 64 groups x 8 members, 8 batch rows/group; A-frag rows 8-15 fed
// duplicated rows (ncol&7), stores masked to quad<2. Groups stay within one
// 64-block dispatch band -> no residency deadlock; members share blk%8 (XCD).
// ---------------------------------------------------------------------------
__global__ __launch_bounds__(128, 1) void enc_kernel(
    const float* __restrict__ Whh, const float* __restrict__ Wih,
    const float* __restrict__ bih, const float* __restrict__ bhh,
    const float* __restrict__ xb,        // [B][S][F] fp32
    bhalf* __restrict__ enc_out,         // [B][S][H]
    float* __restrict__ hcur,            // [B][H] final h, fp32 exact
    unsigned int* __restrict__ hpack,    // [2][B][H] relaxed-atomic channel
    unsigned int* __restrict__ flags)    // [64][8] steps-completed counters
{
  const int tid  = threadIdx.x;
  const int lane = tid & 63;
  const int wv   = tid >> 6;
  const int ncol = lane & 15;
  const int quad = lane >> 4;

  const int blk = blockIdx.x;
  const int g   = (blk & 7) * 8 + (blk >> 6);   // group 0..63 (members share XCD)
  const int w   = (blk >> 3) & 7;               // member 0..7
  const int b0  = g * 8;                        // 8 batch rows per group
  const int iw0 = w * 32;
  const int i0  = iw0 + wv * 16;

  // ---- hi+lo-plane B-frags in registers ----
  bhalf8 bWh[3][9], bWl[3][9];
#pragma unroll
  for (int gg = 0; gg < 3; ++gg) {
    const int jrow = gg * 256 + i0 + ncol;
#pragma unroll
    for (int kt = 0; kt < 9; ++kt) {
      bhalf8 vh = bzero8(), vl = bzero8();
      if (kt < 8) {
        const float* src = Whh + (size_t)jrow * 256 + kt * 32 + quad * 8;
#pragma unroll
        for (int j = 0; j < 8; ++j) {
          const float v = src[j];
          const bhalf h = (bhalf)v;
          vh[j] = h;
          vl[j] = (bhalf)(v - (float)h);
        }
      } else if (quad < 2) {
        const float* src = Wih + (size_t)jrow * 16 + quad * 8;
#pragma unroll
        for (int j = 0; j < 8; ++j) {
          const float v = src[j];
          const bhalf h = (bhalf)v;
          vh[j] = h;
          vl[j] = (bhalf)(v - (float)h);
        }
      }
      bWh[gg][kt] = vh;
      bWl[gg][kt] = vl;
    }
  }

  const int jr = i0 + ncol;
  const float bR  = bih[jr]       + bhh[jr];
  const float bZ  = bih[256 + jr] + bhh[256 + jr];
  const float bNx = bih[512 + jr];
  const float bNh = bhh[512 + jr];

  // batch row for A-fragments: rows 8-15 duplicate rows 0-7 (discarded at store)
  const int bA = b0 + (ncol & 7);
  const int kA = quad * 8;

  float hold[4] = {0.0f, 0.0f, 0.0f, 0.0f};

  for (int t = 0; t < S_; ++t) {
    // x prefetch (independent of flags) — issue before the spin
    bhalf8 xh = bzero8(), xl = bzero8();
    if (quad < 2) {
      const float* xp = xb + ((size_t)bA * S_ + t) * F_ + quad * 8;
#pragma unroll
      for (int j = 0; j < 8; ++j) {
        const float v = __builtin_nontemporal_load(xp + j);
        const bhalf h = (bhalf)v;
        xh[j] = h;
        xl[j] = (bhalf)(v - (float)h);
      }
    }

    f32x4 aR0 = {0,0,0,0}, aR1 = {0,0,0,0}, aR2 = {0,0,0,0};
    f32x4 aZ0 = {0,0,0,0}, aZ1 = {0,0,0,0}, aZ2 = {0,0,0,0};
    f32x4 aN0 = {0,0,0,0}, aN1 = {0,0,0,0}, aN2 = {0,0,0,0};
    f32x4 aNx = {0,0,0,0};

    // kt = 8: x-part (h-independent -> BEFORE the spin)
    aR0 = MFMA16(xh, bWh[0][8], aR0);
    aR1 = MFMA16(xh, bWl[0][8], aR1);
    aR2 = MFMA16(xl, bWh[0][8], aR2);
    aZ0 = MFMA16(xh, bWh[1][8], aZ0);
    aZ1 = MFMA16(xh, bWl[1][8], aZ1);
    aZ2 = MFMA16(xl, bWh[1][8], aZ2);
    aNx = MFMA16(xh, bWh[2][8], aNx);
    aNx = MFMA16(xh, bWl[2][8], aNx);
    aNx = MFMA16(xl, bWh[2][8], aNx);

    if (t > 0) {
      // per-lane divergent spin: lane&7 watches member (lane&7)'s counter.
      const unsigned int* fp = &flags[g * 8 + (lane & 7)];
      while (__hip_atomic_load(fp, __ATOMIC_RELAXED, __HIP_MEMORY_SCOPE_AGENT) <
             (unsigned int)t)
        __builtin_amdgcn_s_sleep(1);

      const int slot = (t - 1) & 1;
      const unsigned long long* hp64 =
          (const unsigned long long*)(hpack + ((size_t)slot * B_ + bA) * H_ + kA);
#pragma unroll
      for (int kt = 0; kt < 8; ++kt) {
        bhalf8 Ah, Al;
#pragma unroll
        for (int j2 = 0; j2 < 4; ++j2) {
          const unsigned long long w2 =
              __hip_atomic_load(hp64 + kt * 16 + j2, __ATOMIC_RELAXED,
                                __HIP_MEMORY_SCOPE_AGENT);
          Ah[2 * j2]     = u16_to_bf((unsigned int)w2);
          Al[2 * j2]     = u16_to_bf((unsigned int)(w2 >> 16));
          Ah[2 * j2 + 1] = u16_to_bf((unsigned int)(w2 >> 32));
          Al[2 * j2 + 1] = u16_to_bf((unsigned int)(w2 >> 48));
        }
        aR0 = MFMA16(Ah, bWh[0][kt], aR0);
        aR1 = MFMA16(Ah, bWl[0][kt], aR1);
        aR2 = MFMA16(Al, bWh[0][kt], aR2);
        aZ0 = MFMA16(Ah, bWh[1][kt], aZ0);
        aZ1 = MFMA16(Ah, bWl[1][kt], aZ1);
        aZ2 = MFMA16(Al, bWh[1][kt], aZ2);
        aN0 = MFMA16(Ah, bWh[2][kt], aN0);
        aN1 = MFMA16(Ah, bWl[2][kt], aN1);
        aN2 = MFMA16(Al, bWh[2][kt], aN2);
      }
    }

    // ---- gates (C/D: col = lane&15, row = quad*4 + reg) ----
    const int iL = i0 + ncol;
    bhalf his[4];
#pragma unroll
    for (int r = 0; r < 4; ++r) {
      const float sR  = aR0[r] + aR1[r] + aR2[r] + bR;
      const float sZ  = aZ0[r] + aZ1[r] + aZ2[r] + bZ;
      const float nhv = aN0[r] + aN1[r] + aN2[r] + bNh;
      const float nxv = aNx[r] + bNx;
      const float rr = sigm(sR);
      const float zz = sigm(sZ);
      const float nn = tanh_f(nxv + rr * nhv);
      const float h2 = (1.0f - zz) * nn + zz * hold[r];
      hold[r] = h2;
      his[r] = (bhalf)h2;
      if (quad < 2) {   // batch rows 0..7 only (rows 8-15 are duplicates)
        const bhalf lo = (bhalf)(h2 - (float)his[r]);
        const int bb = b0 + quad * 4 + r;
        const unsigned int wrd =
            (unsigned int)bf_to_u16(his[r]) | ((unsigned int)bf_to_u16(lo) << 16);
        __hip_atomic_store(&hpack[((size_t)(t & 1) * B_ + bb) * H_ + iL], wrd,
                           __ATOMIC_RELAXED, __HIP_MEMORY_SCOPE_AGENT);
      }
    }

    __syncthreads();   // drains vmcnt(0): hpack stores visible before flag
    if (tid == 0) {
      __hip_atomic_store(&flags[g * 8 + w], (unsigned int)(t + 1),
                         __ATOMIC_RELAXED, __HIP_MEMORY_SCOPE_AGENT);
    }

    // enc_out stores AFTER release (no consumer until dec_kernel).
    if (quad < 2) {
#pragma unroll
      for (int r = 0; r < 4; ++r) {
        const int bb = b0 + quad * 4 + r;
        __builtin_nontemporal_store(his[r], enc_out + ((size_t)bb * S_ + t) * H_ + iL);
      }
    }
  }

  if (quad < 2) {
#pragma unroll
    for (int r = 0; r < 4; ++r)
      hcur[(size_t)(b0 + quad * 4 + r) * H_ + i0 + ncol] = hold[r];
  }
}

// ---------------------------------------------------------------------------
// Prep: dec GRU weights -> TRANSPOSED bf16 pack wbT[64][768][8]:
// wbT[k8][row][j] = (k8*8+j < 256) ? Whh[row][k8*8+j] : Wih[row][k8*8+j-256]
// ---------------------------------------------------------------------------
__global__ __launch_bounds__(256) void wpack_kernel(const float* __restrict__ Whh,
                                                    const float* __restrict__ Wih,
                                                    bhalf* __restrict__ wbT) {
  const int idx = blockIdx.x * 256 + threadIdx.x;
  if (idx >= 64 * 768 * 8) return;
  const int j = idx & 7;
  const int row = (idx >> 3) % 768;
  const int k8 = idx / (768 * 8);
  const int k = k8 * 8 + j;
  const float v = (k < 256) ? Whh[(size_t)row * 256 + k]
                            : Wih[(size_t)row * 256 + (k - 256)];
  wbT[idx] = (bhalf)v;
}

// ---------------------------------------------------------------------------
// Prep: attW -> bf16 TRANSPOSED pack abT[36][336][8] (zero-padded k>=272)
// ---------------------------------------------------------------------------
__global__ __launch_bounds__(256) void apack_kernel(const float* __restrict__ attW,
                                                    bhalf* __restrict__ abT) {
  const int idx = blockIdx.x * 256 + threadIdx.x;
  if (idx >= 36 * 336 * 8) return;
  const int j = idx & 7;
  const int s = (idx >> 3) % 336;
  const int k8 = idx / (8 * 336);
  const int k = k8 * 8 + j;
  abT[idx] = (k < 272) ? (bhalf)attW[(size_t)s * 272 + k] : (bhalf)0.0f;
}

// ---------------------------------------------------------------------------
// Decoder: UNCHANGED from round 2 (verified win: enc_out s<126 LDS cache).
// ---------------------------------------------------------------------------
__global__ __launch_bounds__(256) void dec_kernel(
    const bhalf* __restrict__ wbT,      // [64][768][8]
    const bhalf* __restrict__ abT,      // [36][336][8]
    const float* __restrict__ attb,
    const float* __restrict__ bih, const float* __restrict__ bhh,
    const float* __restrict__ outW, const float* __restrict__ outb,
    const float* __restrict__ linW, const float* __restrict__ linb,
    const bhalf* __restrict__ enc_out, const float* __restrict__ hcur,
    const float* __restrict__ xb, float* __restrict__ dout)
{
  __shared__ __align__(16) bhalf encL[126 * 256];   // 64512 B: s<126 cache
  __shared__ float hyL[288];        // [h(256) | y(16) | 0-pad(16)]
  __shared__ float cL[256];
  __shared__ float sc[S_];
  __shared__ float pC[8][32][9];    // combine partials, padded (bank-safe)
  __shared__ float oP[4][16];
  __shared__ float oF[16];
  __shared__ float red[8];
  const int tid  = threadIdx.x;
  const int lane = tid & 63;
  const int wv   = tid >> 6;
  const int b    = blockIdx.x;
  const int jj   = tid;
  const int cg   = tid & 31;        // combine col-group (8 cols)
  const int ck   = tid >> 5;        // combine s-chunk (42 s)

  // one-time: cache enc_out rows [0,126) for this batch row (coalesced 16B)
  {
    const bhalf8* src = (const bhalf8*)(enc_out + (size_t)b * S_ * H_);
    bhalf8* dst = (bhalf8*)encL;
    for (int it = tid; it < 126 * 32; it += 256) dst[it] = src[it];
  }

  hyL[tid] = hcur[(size_t)b * H_ + tid];
  if (tid < 16) hyL[256 + tid] = xb[((size_t)b * S_ + (S_ - 1)) * F_ + tid];
  else if (tid < 32) hyL[256 + tid] = 0.0f;

  const float bRv  = bih[jj]       + bhh[jj];
  const float bZv  = bih[256 + jj] + bhh[256 + jj];
  const float bNxv = bih[512 + jj];
  const float bNhv = bhh[512 + jj];

  const bhalf* epC = enc_out + ((size_t)b * S_ + ck * 42) * H_ + cg * 8;
  const bhalf* epL = encL + (size_t)(ck * 42) * H_ + cg * 8;
  __syncthreads();

  for (int p = 0; p < P_; ++p) {
    // ---- attention scores (coalesced bf16 weights) ----
    for (int s = tid; s < S_; s += 256) {
      float d0 = 0, d1 = 0, d2 = 0, d3 = 0;
#pragma unroll 4
      for (int k8 = 0; k8 < 36; ++k8) {
        const bhalf8 q = *(const bhalf8*)(abT + ((size_t)k8 * S_ + s) * 8);
        const float* v = hyL + k8 * 8;
        d0 += (float)q[0] * v[0] + (float)q[4] * v[4];
        d1 += (float)q[1] * v[1] + (float)q[5] * v[5];
        d2 += (float)q[2] * v[2] + (float)q[6] * v[6];
        d3 += (float)q[3] * v[3] + (float)q[7] * v[7];
      }
      sc[s] = d0 + d1 + d2 + d3 + attb[s];
    }
    __syncthreads();

    // ---- softmax (all 4 waves) ----
    float mx = -3e38f;
    for (int s = tid; s < S_; s += 256) mx = fmaxf(mx, sc[s]);
#pragma unroll
    for (int o = 32; o > 0; o >>= 1) mx = fmaxf(mx, __shfl_xor(mx, o, 64));
    if (lane == 0) red[wv] = mx;
    __syncthreads();
    mx = fmaxf(fmaxf(red[0], red[1]), fmaxf(red[2], red[3]));
    float sum = 0.0f;
    for (int s = tid; s < S_; s += 256) {
      const float e = __expf(sc[s] - mx);
      sc[s] = e;
      sum += e;
    }
#pragma unroll
    for (int o = 32; o > 0; o >>= 1) sum += __shfl_xor(sum, o, 64);
    if (lane == 0) red[4 + wv] = sum;
    __syncthreads();
    const float inv = fastrcp(red[4] + red[5] + red[6] + red[7]);
    for (int s = tid; s < S_; s += 256) sc[s] *= inv;
    __syncthreads();

    // ---- combine: thread (ck, cg); ck<3 from LDS cache, ck>=3 global ----
    {
      float a0 = 0, a1 = 0, a2 = 0, a3 = 0, a4 = 0, a5 = 0, a6 = 0, a7 = 0;
      const float* scrow = sc + ck * 42;
      if (ck < 3) {
#pragma unroll 6
        for (int s5 = 0; s5 < 42; ++s5) {
          const bhalf8 v = *(const bhalf8*)(epL + (size_t)s5 * H_);
          const float wgt = scrow[s5];
          a0 += wgt * (float)v[0];
          a1 += wgt * (float)v[1];
          a2 += wgt * (float)v[2];
          a3 += wgt * (float)v[3];
          a4 += wgt * (float)v[4];
          a5 += wgt * (float)v[5];
          a6 += wgt * (float)v[6];
          a7 += wgt * (float)v[7];
        }
      } else {
#pragma unroll 6
        for (int s5 = 0; s5 < 42; ++s5) {
          const bhalf8 v = *(const bhalf8*)(epC + (size_t)s5 * H_);
          const float wgt = scrow[s5];
          a0 += wgt * (float)v[0];
          a1 += wgt * (float)v[1];
          a2 += wgt * (float)v[2];
          a3 += wgt * (float)v[3];
          a4 += wgt * (float)v[4];
          a5 += wgt * (float)v[5];
          a6 += wgt * (float)v[6];
          a7 += wgt * (float)v[7];
        }
      }
      float* pp = pC[ck][cg];
      pp[0] = a0; pp[1] = a1; pp[2] = a2; pp[3] = a3;
      pp[4] = a4; pp[5] = a5; pp[6] = a6; pp[7] = a7;
    }
    __syncthreads();
    {
      float s = 0.0f;
      const int gg = jj >> 3, j = jj & 7;
#pragma unroll
      for (int c = 0; c < 8; ++c) s += pC[c][gg][j];
      cL[jj] = s;
    }
    __syncthreads();

    // ---- GRU: full-K in registers (rows jj, 256+jj, 512+jj of wbT) ----
    float hnew;
    {
      float r0 = 0, r1 = 0, z0 = 0, z1 = 0, nh0 = 0, nh1 = 0, nx0 = 0, nx1 = 0;
#pragma unroll 4
      for (int k8 = 0; k8 < 32; ++k8) {          // h part
        const bhalf* base = wbT + ((size_t)k8 * 768) * 8;
        const bhalf8 qR = *(const bhalf8*)(base + (size_t)jj * 8);
        const bhalf8 qZ = *(const bhalf8*)(base + (size_t)(256 + jj) * 8);
        const bhalf8 qN = *(const bhalf8*)(base + (size_t)(512 + jj) * 8);
        const float* v = hyL + k8 * 8;
        r0 += (float)qR[0]*v[0] + (float)qR[2]*v[2] + (float)qR[4]*v[4] + (float)qR[6]*v[6];
        r1 += (float)qR[1]*v[1] + (float)qR[3]*v[3] + (float)qR[5]*v[5] + (float)qR[7]*v[7];
        z0 += (float)qZ[0]*v[0] + (float)qZ[2]*v[2] + (float)qZ[4]*v[4] + (float)qZ[6]*v[6];
        z1 += (float)qZ[1]*v[1] + (float)qZ[3]*v[3] + (float)qZ[5]*v[5] + (float)qZ[7]*v[7];
        nh0 += (float)qN[0]*v[0] + (float)qN[2]*v[2] + (float)qN[4]*v[4] + (float)qN[6]*v[6];
        nh1 += (float)qN[1]*v[1] + (float)qN[3]*v[3] + (float)qN[5]*v[5] + (float)qN[7]*v[7];
      }
#pragma unroll 4
      for (int k8 = 32; k8 < 64; ++k8) {         // c part
        const bhalf* base = wbT + ((size_t)k8 * 768) * 8;
        const bhalf8 qR = *(const bhalf8*)(base + (size_t)jj * 8);
        const bhalf8 qZ = *(const bhalf8*)(base + (size_t)(256 + jj) * 8);
        const bhalf8 qN = *(const bhalf8*)(base + (size_t)(512 + jj) * 8);
        const float* v = cL + (k8 - 32) * 8;
        r0 += (float)qR[0]*v[0] + (float)qR[2]*v[2] + (float)qR[4]*v[4] + (float)qR[6]*v[6];
        r1 += (float)qR[1]*v[1] + (float)qR[3]*v[3] + (float)qR[5]*v[5] + (float)qR[7]*v[7];
        z0 += (float)qZ[0]*v[0] + (float)qZ[2]*v[2] + (float)qZ[4]*v[4] + (float)qZ[6]*v[6];
        z1 += (float)qZ[1]*v[1] + (float)qZ[3]*v[3] + (float)qZ[5]*v[5] + (float)qZ[7]*v[7];
        nx0 += (float)qN[0]*v[0] + (float)qN[2]*v[2] + (float)qN[4]*v[4] + (float)qN[6]*v[6];
        nx1 += (float)qN[1]*v[1] + (float)qN[3]*v[3] + (float)qN[5]*v[5] + (float)qN[7]*v[7];
      }
      const float sR = r0 + r1 + bRv;
      const float sZ = z0 + z1 + bZv;
      const float nh = nh0 + nh1 + bNhv;
      const float nx = nx0 + nx1 + bNxv;
      const float rr = 1.0f / (1.0f + __expf(-sR));
      const float zz = 1.0f / (1.0f + __expf(-sZ));
      const float nn = tanhf(nx + rr * nh);
      hnew = (1.0f - zz) * nn + zz * hyL[jj];
    }
    __syncthreads();   // all hyL reads complete
    hyL[jj] = hnew;
    __syncthreads();

    // ---- out: 64 threads, 4-way K split ----
    if (tid < 64) {
      const int f = tid & 15, q = tid >> 4;
      const float* wr = outW + (size_t)f * H_ + q * 64;
      const float* hv = hyL + q * 64;
      float a0 = 0, a1 = 0, a2 = 0, a3 = 0;
#pragma unroll 4
      for (int k = 0; k < 64; k += 4) {
        a0 += wr[k]     * hv[k];
        a1 += wr[k + 1] * hv[k + 1];
        a2 += wr[k + 2] * hv[k + 2];
        a3 += wr[k + 3] * hv[k + 3];
      }
      oP[q][f] = a0 + a1 + a2 + a3;
    }
    __syncthreads();
    if (tid < 16) {
      const float o = oP[0][tid] + oP[1][tid] + oP[2][tid] + oP[3][tid] + outb[tid];
      oF[tid] = o;
      hyL[256 + tid] = o;    // y feedback
    }
    __syncthreads();
    if (tid == 0) {
      float pr = linb[0];
#pragma unroll
      for (int f = 0; f < 16; ++f) pr += oF[f] * linW[f];
      dout[(size_t)b * P_ + p] = pr;
    }
  }
}

// ---------------------------------------------------------------------------
extern "C" void kernel_launch(void* const* d_in, const int* in_sizes, int n_in,
                              void* d_out, int out_size, void* d_ws, size_t ws_size,
                              hipStream_t stream)
{
  (void)in_sizes; (void)n_in; (void)out_size;
  const float* xb      = (const float*)d_in[0];
  const float* enc_Wih = (const float*)d_in[1];
  const float* enc_Whh = (const float*)d_in[2];
  const float* enc_bih = (const float*)d_in[3];
  const float* enc_bhh = (const float*)d_in[4];
  const float* att_W   = (const float*)d_in[5];
  const float* att_b   = (const float*)d_in[6];
  const float* dec_Wih = (const float*)d_in[7];
  const float* dec_Whh = (const float*)d_in[8];
  const float* dec_bih = (const float*)d_in[9];
  const float* dec_bhh = (const float*)d_in[10];
  const float* out_W   = (const float*)d_in[11];
  const float* out_b   = (const float*)d_in[12];
  const float* lin_W   = (const float*)d_in[13];
  const float* lin_b   = (const float*)d_in[14];
  float* dout = (float*)d_out;

  char* ws = (char*)d_ws;
  const size_t off_enc = 0;                                     // bf16 enc_out
  const size_t off_hp  = off_enc + (size_t)B_ * S_ * H_ * 2;    // 88,080,384
  const size_t off_hc  = off_hp + (size_t)2 * B_ * H_ * 4;      // hpack u32
  const size_t off_wb  = off_hc + (size_t)B_ * H_ * 4;
  const size_t off_ab  = off_wb + (size_t)64 * 768 * 8 * 2;
  const size_t off_fl  = off_ab + (size_t)36 * 336 * 8 * 2;
  const size_t need    = off_fl + 64 * 8 * sizeof(unsigned int);
  if (ws_size < need) return;

  bhalf* enc_out      = (bhalf*)(ws + off_enc);
  unsigned int* hpack = (unsigned int*)(ws + off_hp);
  float* hcur         = (float*)(ws + off_hc);
  bhalf* wbT          = (bhalf*)(ws + off_wb);
  bhalf* abT          = (bhalf*)(ws + off_ab);
  unsigned int* flags = (unsigned int*)(ws + off_fl);

  (void)hipMemsetAsync(flags, 0, 64 * 8 * sizeof(unsigned int), stream);
  wpack_kernel<<<(64 * 768 * 8 + 255) / 256, 256, 0, stream>>>(dec_Whh, dec_Wih, wbT);
  apack_kernel<<<(36 * 336 * 8 + 255) / 256, 256, 0, stream>>>(att_W, abT);
  enc_kernel<<<512, 128, 0, stream>>>(enc_Whh, enc_Wih, enc_bih, enc_bhh, xb,
                                      enc_out, hcur, hpack, flags);
  dec_kernel<<<B_, 256, 0, stream>>>(wbT, abT, att_b, dec_bih, dec_bhh,
                                     out_W, out_b, lin_W, lin_b,
                                     enc_out, hcur, xb, dout);
}

// Round 6
// 3011.950 us; speedup vs baseline: 1.1240x; 1.1240x over previous
//
#include <hip/hip_runtime.h>
#include <cstdint>
#include <cstddef>

#define B_ 512
#define S_ 336
#define F_ 16
#define H_ 256
#define P_ 48

typedef __bf16 bhalf;
typedef __attribute__((ext_vector_type(8))) __bf16 bhalf8;
typedef __attribute__((ext_vector_type(4))) float f32x4;

#define MFMA16(A, Bv, C) __builtin_amdgcn_mfma_f32_16x16x32_bf16((A), (Bv), (C), 0, 0, 0)

__device__ __forceinline__ float fastrcp(float x) { return __builtin_amdgcn_rcpf(x); }
__device__ __forceinline__ float sigm(float x) { return fastrcp(1.0f + __expf(-x)); }
__device__ __forceinline__ float tanh_f(float x) { return 2.0f * fastrcp(1.0f + __expf(-2.0f * x)) - 1.0f; }

__device__ __forceinline__ bhalf u16_to_bf(unsigned int u) {
  return __builtin_bit_cast(__bf16, (unsigned short)u);
}
__device__ __forceinline__ unsigned short bf_to_u16(bhalf b) {
  return __builtin_bit_cast(unsigned short, b);
}

__device__ __forceinline__ bhalf8 bzero8() {
  bhalf8 v;
#pragma unroll
  for (int j = 0; j < 8; ++j) v[j] = (bhalf)0.0f;
  return v;
}

// ---------------------------------------------------------------------------
// Encoder: weight-stationary MFMA flag pipeline.
// GEOMETRY = r4 (256 blocks, 32 groups x 16 rows — r5's 2-blocks/CU refuted:
// utilization doubled but duration worsened, duplicated compute).
// CHANGE vs r4 (ONE mechanism): batched hpack consume. The old loop issued
// 4 atomic loads per kt, consumed immediately by that kt's MFMAs -> compiler
// emits 8 serialized {load, waitcnt, MFMA} groups = 8 agent-scope (L2-bypass)
// round trips ~6-7Kcy of the 11.7Kcy step. Now: all 32 loads issue into
// wbuf[32] (static idx -> registers), ONE latency wait, then unpack+MFMA.
// ---------------------------------------------------------------------------
__global__ __launch_bounds__(128, 1) void enc_kernel(
    const float* __restrict__ Whh, const float* __restrict__ Wih,
    const float* __restrict__ bih, const float* __restrict__ bhh,
    const float* __restrict__ xb,        // [B][S][F] fp32
    bhalf* __restrict__ enc_out,         // [B][S][H]
    float* __restrict__ hcur,            // [B][H] final h, fp32 exact
    unsigned int* __restrict__ hpack,    // [2][B][H] relaxed-atomic channel
    unsigned int* __restrict__ flags)    // [32][8] steps-completed counters
{
  const int tid  = threadIdx.x;
  const int lane = tid & 63;
  const int wv   = tid >> 6;
  const int ncol = lane & 15;
  const int quad = lane >> 4;

  const int blk = blockIdx.x;
  const int g   = (blk & 7) * 4 + (blk >> 6);   // group 0..31 (members share XCD)
  const int w   = (blk >> 3) & 7;               // member 0..7
  const int b0  = g * 16;
  const int iw0 = w * 32;
  const int i0  = iw0 + wv * 16;

  // ---- hi+lo-plane B-frags in registers ----
  bhalf8 bWh[3][9], bWl[3][9];
#pragma unroll
  for (int gg = 0; gg < 3; ++gg) {
    const int jrow = gg * 256 + i0 + ncol;
#pragma unroll
    for (int kt = 0; kt < 9; ++kt) {
      bhalf8 vh = bzero8(), vl = bzero8();
      if (kt < 8) {
        const float* src = Whh + (size_t)jrow * 256 + kt * 32 + quad * 8;
#pragma unroll
        for (int j = 0; j < 8; ++j) {
          const float v = src[j];
          const bhalf h = (bhalf)v;
          vh[j] = h;
          vl[j] = (bhalf)(v - (float)h);
        }
      } else if (quad < 2) {
        const float* src = Wih + (size_t)jrow * 16 + quad * 8;
#pragma unroll
        for (int j = 0; j < 8; ++j) {
          const float v = src[j];
          const bhalf h = (bhalf)v;
          vh[j] = h;
          vl[j] = (bhalf)(v - (float)h);
        }
      }
      bWh[gg][kt] = vh;
      bWl[gg][kt] = vl;
    }
  }

  const int jr = i0 + ncol;
  const float bR  = bih[jr]       + bhh[jr];
  const float bZ  = bih[256 + jr] + bhh[256 + jr];
  const float bNx = bih[512 + jr];
  const float bNh = bhh[512 + jr];

  const int bA = b0 + ncol;
  const int kA = quad * 8;

  float hold[4] = {0.0f, 0.0f, 0.0f, 0.0f};

  for (int t = 0; t < S_; ++t) {
    // x prefetch (independent of flags) — issue before the spin
    bhalf8 xh = bzero8(), xl = bzero8();
    if (quad < 2) {
      const float* xp = xb + ((size_t)bA * S_ + t) * F_ + quad * 8;
#pragma unroll
      for (int j = 0; j < 8; ++j) {
        const float v = __builtin_nontemporal_load(xp + j);
        const bhalf h = (bhalf)v;
        xh[j] = h;
        xl[j] = (bhalf)(v - (float)h);
      }
    }

    f32x4 aR0 = {0,0,0,0}, aR1 = {0,0,0,0}, aR2 = {0,0,0,0};
    f32x4 aZ0 = {0,0,0,0}, aZ1 = {0,0,0,0}, aZ2 = {0,0,0,0};
    f32x4 aN0 = {0,0,0,0}, aN1 = {0,0,0,0}, aN2 = {0,0,0,0};
    f32x4 aNx = {0,0,0,0};

    // kt = 8: x-part (h-independent -> BEFORE the spin)
    aR0 = MFMA16(xh, bWh[0][8], aR0);
    aR1 = MFMA16(xh, bWl[0][8], aR1);
    aR2 = MFMA16(xl, bWh[0][8], aR2);
    aZ0 = MFMA16(xh, bWh[1][8], aZ0);
    aZ1 = MFMA16(xh, bWl[1][8], aZ1);
    aZ2 = MFMA16(xl, bWh[1][8], aZ2);
    aNx = MFMA16(xh, bWh[2][8], aNx);
    aNx = MFMA16(xh, bWl[2][8], aNx);
    aNx = MFMA16(xl, bWh[2][8], aNx);

    if (t > 0) {
      // per-lane divergent spin: lane&7 watches member (lane&7)'s counter.
      const unsigned int* fp = &flags[g * 8 + (lane & 7)];
      while (__hip_atomic_load(fp, __ATOMIC_RELAXED, __HIP_MEMORY_SCOPE_AGENT) <
             (unsigned int)t)
        __builtin_amdgcn_s_sleep(1);

      const int slot = (t - 1) & 1;
      const unsigned long long* hp64 =
          (const unsigned long long*)(hpack + ((size_t)slot * B_ + bA) * H_ + kA);

      // ---- phase 1: issue ALL 32 loads (one L3 latency, 32 in flight) ----
      unsigned long long wbuf[32];
#pragma unroll
      for (int i = 0; i < 32; ++i)
        wbuf[i] = __hip_atomic_load(hp64 + (i >> 2) * 16 + (i & 3),
                                    __ATOMIC_RELAXED, __HIP_MEMORY_SCOPE_AGENT);

      // ---- phase 2: unpack + MFMA ----
#pragma unroll
      for (int kt = 0; kt < 8; ++kt) {
        bhalf8 Ah, Al;
#pragma unroll
        for (int j2 = 0; j2 < 4; ++j2) {
          const unsigned long long w2 = wbuf[kt * 4 + j2];
          Ah[2 * j2]     = u16_to_bf((unsigned int)w2);
          Al[2 * j2]     = u16_to_bf((unsigned int)(w2 >> 16));
          Ah[2 * j2 + 1] = u16_to_bf((unsigned int)(w2 >> 32));
          Al[2 * j2 + 1] = u16_to_bf((unsigned int)(w2 >> 48));
        }
        aR0 = MFMA16(Ah, bWh[0][kt], aR0);
        aR1 = MFMA16(Ah, bWl[0][kt], aR1);
        aR2 = MFMA16(Al, bWh[0][kt], aR2);
        aZ0 = MFMA16(Ah, bWh[1][kt], aZ0);
        aZ1 = MFMA16(Ah, bWl[1][kt], aZ1);
        aZ2 = MFMA16(Al, bWh[1][kt], aZ2);
        aN0 = MFMA16(Ah, bWh[2][kt], aN0);
        aN1 = MFMA16(Ah, bWl[2][kt], aN1);
        aN2 = MFMA16(Al, bWh[2][kt], aN2);
      }
    }

    // ---- gates (C/D: col = lane&15, row = quad*4 + reg) ----
    const int iL = i0 + ncol;
    bhalf his[4];
#pragma unroll
    for (int r = 0; r < 4; ++r) {
      const float sR  = aR0[r] + aR1[r] + aR2[r] + bR;
      const float sZ  = aZ0[r] + aZ1[r] + aZ2[r] + bZ;
      const float nhv = aN0[r] + aN1[r] + aN2[r] + bNh;
      const float nxv = aNx[r] + bNx;
      const float rr = sigm(sR);
      const float zz = sigm(sZ);
      const float nn = tanh_f(nxv + rr * nhv);
      const float h2 = (1.0f - zz) * nn + zz * hold[r];
      hold[r] = h2;
      his[r] = (bhalf)h2;
      const bhalf lo = (bhalf)(h2 - (float)his[r]);
      const int bb = b0 + quad * 4 + r;
      const unsigned int wrd =
          (unsigned int)bf_to_u16(his[r]) | ((unsigned int)bf_to_u16(lo) << 16);
      __hip_atomic_store(&hpack[((size_t)(t & 1) * B_ + bb) * H_ + iL], wrd,
                         __ATOMIC_RELAXED, __HIP_MEMORY_SCOPE_AGENT);
    }

    __syncthreads();   // drains vmcnt(0): hpack stores visible before flag
    if (tid == 0) {
      __hip_atomic_store(&flags[g * 8 + w], (unsigned int)(t + 1),
                         __ATOMIC_RELAXED, __HIP_MEMORY_SCOPE_AGENT);
    }

    // enc_out stores AFTER release (no consumer until dec_kernel).
#pragma unroll
    for (int r = 0; r < 4; ++r) {
      const int bb = b0 + quad * 4 + r;
      __builtin_nontemporal_store(his[r], enc_out + ((size_t)bb * S_ + t) * H_ + iL);
    }
  }

#pragma unroll
  for (int r = 0; r < 4; ++r)
    hcur[(size_t)(b0 + quad * 4 + r) * H_ + i0 + ncol] = hold[r];
}

// ---------------------------------------------------------------------------
// Prep: dec GRU weights -> TRANSPOSED bf16 pack wbT[64][768][8]:
// wbT[k8][row][j] = (k8*8+j < 256) ? Whh[row][k8*8+j] : Wih[row][k8*8+j-256]
// ---------------------------------------------------------------------------
__global__ __launch_bounds__(256) void wpack_kernel(const float* __restrict__ Whh,
                                                    const float* __restrict__ Wih,
                                                    bhalf* __restrict__ wbT) {
  const int idx = blockIdx.x * 256 + threadIdx.x;
  if (idx >= 64 * 768 * 8) return;
  const int j = idx & 7;
  const int row = (idx >> 3) % 768;
  const int k8 = idx / (768 * 8);
  const int k = k8 * 8 + j;
  const float v = (k < 256) ? Whh[(size_t)row * 256 + k]
                            : Wih[(size_t)row * 256 + (k - 256)];
  wbT[idx] = (bhalf)v;
}

// ---------------------------------------------------------------------------
// Prep: attW -> bf16 TRANSPOSED pack abT[36][336][8] (zero-padded k>=272)
// ---------------------------------------------------------------------------
__global__ __launch_bounds__(256) void apack_kernel(const float* __restrict__ attW,
                                                    bhalf* __restrict__ abT) {
  const int idx = blockIdx.x * 256 + threadIdx.x;
  if (idx >= 36 * 336 * 8) return;
  const int j = idx & 7;
  const int s = (idx >> 3) % 336;
  const int k8 = idx / (8 * 336);
  const int k = k8 * 8 + j;
  abT[idx] = (k < 272) ? (bhalf)attW[(size_t)s * 272 + k] : (bhalf)0.0f;
}

// ---------------------------------------------------------------------------
// Decoder: UNCHANGED from round 2 (verified win: enc_out s<126 LDS cache).
// ---------------------------------------------------------------------------
__global__ __launch_bounds__(256) void dec_kernel(
    const bhalf* __restrict__ wbT,      // [64][768][8]
    const bhalf* __restrict__ abT,      // [36][336][8]
    const float* __restrict__ attb,
    const float* __restrict__ bih, const float* __restrict__ bhh,
    const float* __restrict__ outW, const float* __restrict__ outb,
    const float* __restrict__ linW, const float* __restrict__ linb,
    const bhalf* __restrict__ enc_out, const float* __restrict__ hcur,
    const float* __restrict__ xb, float* __restrict__ dout)
{
  __shared__ __align__(16) bhalf encL[126 * 256];   // 64512 B: s<126 cache
  __shared__ float hyL[288];        // [h(256) | y(16) | 0-pad(16)]
  __shared__ float cL[256];
  __shared__ float sc[S_];
  __shared__ float pC[8][32][9];    // combine partials, padded (bank-safe)
  __shared__ float oP[4][16];
  __shared__ float oF[16];
  __shared__ float red[8];
  const int tid  = threadIdx.x;
  const int lane = tid & 63;
  const int wv   = tid >> 6;
  const int b    = blockIdx.x;
  const int jj   = tid;
  const int cg   = tid & 31;        // combine col-group (8 cols)
  const int ck   = tid >> 5;        // combine s-chunk (42 s)

  // one-time: cache enc_out rows [0,126) for this batch row (coalesced 16B)
  {
    const bhalf8* src = (const bhalf8*)(enc_out + (size_t)b * S_ * H_);
    bhalf8* dst = (bhalf8*)encL;
    for (int it = tid; it < 126 * 32; it += 256) dst[it] = src[it];
  }

  hyL[tid] = hcur[(size_t)b * H_ + tid];
  if (tid < 16) hyL[256 + tid] = xb[((size_t)b * S_ + (S_ - 1)) * F_ + tid];
  else if (tid < 32) hyL[256 + tid] = 0.0f;

  const float bRv  = bih[jj]       + bhh[jj];
  const float bZv  = bih[256 + jj] + bhh[256 + jj];
  const float bNxv = bih[512 + jj];
  const float bNhv = bhh[512 + jj];

  const bhalf* epC = enc_out + ((size_t)b * S_ + ck * 42) * H_ + cg * 8;
  const bhalf* epL = encL + (size_t)(ck * 42) * H_ + cg * 8;
  __syncthreads();

  for (int p = 0; p < P_; ++p) {
    // ---- attention scores (coalesced bf16 weights) ----
    for (int s = tid; s < S_; s += 256) {
      float d0 = 0, d1 = 0, d2 = 0, d3 = 0;
#pragma unroll 4
      for (int k8 = 0; k8 < 36; ++k8) {
        const bhalf8 q = *(const bhalf8*)(abT + ((size_t)k8 * S_ + s) * 8);
        const float* v = hyL + k8 * 8;
        d0 += (float)q[0] * v[0] + (float)q[4] * v[4];
        d1 += (float)q[1] * v[1] + (float)q[5] * v[5];
        d2 += (float)q[2] * v[2] + (float)q[6] * v[6];
        d3 += (float)q[3] * v[3] + (float)q[7] * v[7];
      }
      sc[s] = d0 + d1 + d2 + d3 + attb[s];
    }
    __syncthreads();

    // ---- softmax (all 4 waves) ----
    float mx = -3e38f;
    for (int s = tid; s < S_; s += 256) mx = fmaxf(mx, sc[s]);
#pragma unroll
    for (int o = 32; o > 0; o >>= 1) mx = fmaxf(mx, __shfl_xor(mx, o, 64));
    if (lane == 0) red[wv] = mx;
    __syncthreads();
    mx = fmaxf(fmaxf(red[0], red[1]), fmaxf(red[2], red[3]));
    float sum = 0.0f;
    for (int s = tid; s < S_; s += 256) {
      const float e = __expf(sc[s] - mx);
      sc[s] = e;
      sum += e;
    }
#pragma unroll
    for (int o = 32; o > 0; o >>= 1) sum += __shfl_xor(sum, o, 64);
    if (lane == 0) red[4 + wv] = sum;
    __syncthreads();
    const float inv = fastrcp(red[4] + red[5] + red[6] + red[7]);
    for (int s = tid; s < S_; s += 256) sc[s] *= inv;
    __syncthreads();

    // ---- combine: thread (ck, cg); ck<3 from LDS cache, ck>=3 global ----
    {
      float a0 = 0, a1 = 0, a2 = 0, a3 = 0, a4 = 0, a5 = 0, a6 = 0, a7 = 0;
      const float* scrow = sc + ck * 42;
      if (ck < 3) {
#pragma unroll 6
        for (int s5 = 0; s5 < 42; ++s5) {
          const bhalf8 v = *(const bhalf8*)(epL + (size_t)s5 * H_);
          const float wgt = scrow[s5];
          a0 += wgt * (float)v[0];
          a1 += wgt * (float)v[1];
          a2 += wgt * (float)v[2];
          a3 += wgt * (float)v[3];
          a4 += wgt * (float)v[4];
          a5 += wgt * (float)v[5];
          a6 += wgt * (float)v[6];
          a7 += wgt * (float)v[7];
        }
      } else {
#pragma unroll 6
        for (int s5 = 0; s5 < 42; ++s5) {
          const bhalf8 v = *(const bhalf8*)(epC + (size_t)s5 * H_);
          const float wgt = scrow[s5];
          a0 += wgt * (float)v[0];
          a1 += wgt * (float)v[1];
          a2 += wgt * (float)v[2];
          a3 += wgt * (float)v[3];
          a4 += wgt * (float)v[4];
          a5 += wgt * (float)v[5];
          a6 += wgt * (float)v[6];
          a7 += wgt * (float)v[7];
        }
      }
      float* pp = pC[ck][cg];
      pp[0] = a0; pp[1] = a1; pp[2] = a2; pp[3] = a3;
      pp[4] = a4; pp[5] = a5; pp[6] = a6; pp[7] = a7;
    }
    __syncthreads();
    {
      float s = 0.0f;
      const int gg = jj >> 3, j = jj & 7;
#pragma unroll
      for (int c = 0; c < 8; ++c) s += pC[c][gg][j];
      cL[jj] = s;
    }
    __syncthreads();

    // ---- GRU: full-K in registers (rows jj, 256+jj, 512+jj of wbT) ----
    float hnew;
    {
      float r0 = 0, r1 = 0, z0 = 0, z1 = 0, nh0 = 0, nh1 = 0, nx0 = 0, nx1 = 0;
#pragma unroll 4
      for (int k8 = 0; k8 < 32; ++k8) {          // h part
        const bhalf* base = wbT + ((size_t)k8 * 768) * 8;
        const bhalf8 qR = *(const bhalf8*)(base + (size_t)jj * 8);
        const bhalf8 qZ = *(const bhalf8*)(base + (size_t)(256 + jj) * 8);
        const bhalf8 qN = *(const bhalf8*)(base + (size_t)(512 + jj) * 8);
        const float* v = hyL + k8 * 8;
        r0 += (float)qR[0]*v[0] + (float)qR[2]*v[2] + (float)qR[4]*v[4] + (float)qR[6]*v[6];
        r1 += (float)qR[1]*v[1] + (float)qR[3]*v[3] + (float)qR[5]*v[5] + (float)qR[7]*v[7];
        z0 += (float)qZ[0]*v[0] + (float)qZ[2]*v[2] + (float)qZ[4]*v[4] + (float)qZ[6]*v[6];
        z1 += (float)qZ[1]*v[1] + (float)qZ[3]*v[3] + (float)qZ[5]*v[5] + (float)qZ[7]*v[7];
        nh0 += (float)qN[0]*v[0] + (float)qN[2]*v[2] + (float)qN[4]*v[4] + (float)qN[6]*v[6];
        nh1 += (float)qN[1]*v[1] + (float)qN[3]*v[3] + (float)qN[5]*v[5] + (float)qN[7]*v[7];
      }
#pragma unroll 4
      for (int k8 = 32; k8 < 64; ++k8) {         // c part
        const bhalf* base = wbT + ((size_t)k8 * 768) * 8;
        const bhalf8 qR = *(const bhalf8*)(base + (size_t)jj * 8);
        const bhalf8 qZ = *(const bhalf8*)(base + (size_t)(256 + jj) * 8);
        const bhalf8 qN = *(const bhalf8*)(base + (size_t)(512 + jj) * 8);
        const float* v = cL + (k8 - 32) * 8;
        r0 += (float)qR[0]*v[0] + (float)qR[2]*v[2] + (float)qR[4]*v[4] + (float)qR[6]*v[6];
        r1 += (float)qR[1]*v[1] + (float)qR[3]*v[3] + (float)qR[5]*v[5] + (float)qR[7]*v[7];
        z0 += (float)qZ[0]*v[0] + (float)qZ[2]*v[2] + (float)qZ[4]*v[4] + (float)qZ[6]*v[6];
        z1 += (float)qZ[1]*v[1] + (float)qZ[3]*v[3] + (float)qZ[5]*v[5] + (float)qZ[7]*v[7];
        nx0 += (float)qN[0]*v[0] + (float)qN[2]*v[2] + (float)qN[4]*v[4] + (float)qN[6]*v[6];
        nx1 += (float)qN[1]*v[1] + (float)qN[3]*v[3] + (float)qN[5]*v[5] + (float)qN[7]*v[7];
      }
      const float sR = r0 + r1 + bRv;
      const float sZ = z0 + z1 + bZv;
      const float nh = nh0 + nh1 + bNhv;
      const float nx = nx0 + nx1 + bNxv;
      const float rr = 1.0f / (1.0f + __expf(-sR));
      const float zz = 1.0f / (1.0f + __expf(-sZ));
      const float nn = tanhf(nx + rr * nh);
      hnew = (1.0f - zz) * nn + zz * hyL[jj];
    }
    __syncthreads();   // all hyL reads complete
    hyL[jj] = hnew;
    __syncthreads();

    // ---- out: 64 threads, 4-way K split ----
    if (tid < 64) {
      const int f = tid & 15, q = tid >> 4;
      const float* wr = outW + (size_t)f * H_ + q * 64;
      const float* hv = hyL + q * 64;
      float a0 = 0, a1 = 0, a2 = 0, a3 = 0;
#pragma unroll 4
      for (int k = 0; k < 64; k += 4) {
        a0 += wr[k]     * hv[k];
        a1 += wr[k + 1] * hv[k + 1];
        a2 += wr[k + 2] * hv[k + 2];
        a3 += wr[k + 3] * hv[k + 3];
      }
      oP[q][f] = a0 + a1 + a2 + a3;
    }
    __syncthreads();
    if (tid < 16) {
      const float o = oP[0][tid] + oP[1][tid] + oP[2][tid] + oP[3][tid] + outb[tid];
      oF[tid] = o;
      hyL[256 + tid] = o;    // y feedback
    }
    __syncthreads();
    if (tid == 0) {
      float pr = linb[0];
#pragma unroll
      for (int f = 0; f < 16; ++f) pr += oF[f] * linW[f];
      dout[(size_t)b * P_ + p] = pr;
    }
  }
}

// ---------------------------------------------------------------------------
extern "C" void kernel_launch(void* const* d_in, const int* in_sizes, int n_in,
                              void* d_out, int out_size, void* d_ws, size_t ws_size,
                              hipStream_t stream)
{
  (void)in_sizes; (void)n_in; (void)out_size;
  const float* xb      = (const float*)d_in[0];
  const float* enc_Wih = (const float*)d_in[1];
  const float* enc_Whh = (const float*)d_in[2];
  const float* enc_bih = (const float*)d_in[3];
  const float* enc_bhh = (const float*)d_in[4];
  const float* att_W   = (const float*)d_in[5];
  const float* att_b   = (const float*)d_in[6];
  const float* dec_Wih = (const float*)d_in[7];
  const float* dec_Whh = (const float*)d_in[8];
  const float* dec_bih = (const float*)d_in[9];
  const float* dec_bhh = (const float*)d_in[10];
  const float* out_W   = (const float*)d_in[11];
  const float* out_b   = (const float*)d_in[12];
  const float* lin_W   = (const float*)d_in[13];
  const float* lin_b   = (const float*)d_in[14];
  float* dout = (float*)d_out;

  char* ws = (char*)d_ws;
  const size_t off_enc = 0;                                     // bf16 enc_out
  const size_t off_hp  = off_enc + (size_t)B_ * S_ * H_ * 2;    // 88,080,384
  const size_t off_hc  = off_hp + (size_t)2 * B_ * H_ * 4;      // hpack u32
  const size_t off_wb  = off_hc + (size_t)B_ * H_ * 4;
  const size_t off_ab  = off_wb + (size_t)64 * 768 * 8 * 2;
  const size_t off_fl  = off_ab + (size_t)36 * 336 * 8 * 2;
  const size_t need    = off_fl + 32 * 8 * sizeof(unsigned int);
  if (ws_size < need) return;

  bhalf* enc_out      = (bhalf*)(ws + off_enc);
  unsigned int* hpack = (unsigned int*)(ws + off_hp);
  float* hcur         = (float*)(ws + off_hc);
  bhalf* wbT          = (bhalf*)(ws + off_wb);
  bhalf* abT          = (bhalf*)(ws + off_ab);
  unsigned int* flags = (unsigned int*)(ws + off_fl);

  (void)hipMemsetAsync(flags, 0, 32 * 8 * sizeof(unsigned int), stream);
  wpack_kernel<<<(64 * 768 * 8 + 255) / 256, 256, 0, stream>>>(dec_Whh, dec_Wih, wbT);
  apack_kernel<<<(36 * 336 * 8 + 255) / 256, 256, 0, stream>>>(att_W, abT);
  enc_kernel<<<256, 128, 0, stream>>>(enc_Whh, enc_Wih, enc_bih, enc_bhh, xb,
                                      enc_out, hcur, hpack, flags);
  dec_kernel<<<B_, 256, 0, stream>>>(wbT, abT, att_b, dec_bih, dec_bhh,
                                     out_W, out_b, lin_W, lin_b,
                                     enc_out, hcur, xb, dout);
}